// Round 1
// baseline (500.308 us; speedup 1.0000x reference)
//
#include <hip/hip_runtime.h>
#include <hip/hip_bf16.h>

// One-hot expansion: mask [1,1,256,256,48] fp32 labels in 0..40 ->
// out [1,40,256,256,48] fp32, out[n,v] = (mask[v] == n+1).
// Memory-bound: 12.6 MB read, 503 MB write. Each thread handles 4 voxels
// (float4), emitting 40 coalesced float4 stores (one per label plane).

constexpr int V = 256 * 256 * 48;   // 3,145,728 voxels
constexpr int N_LABELS = 40;

__global__ __launch_bounds__(256)
void onehot_kernel(const float* __restrict__ mask, float* __restrict__ out) {
    const int i = (blockIdx.x * blockDim.x + threadIdx.x) * 4;  // voxel index
    // i < V guaranteed: V/4 = 786432 threads exactly, grid sized to match.
    const float4 m = *reinterpret_cast<const float4*>(mask + i);

#pragma unroll
    for (int n = 0; n < N_LABELS; ++n) {
        const float lab = (float)(n + 1);
        float4 o;
        o.x = (m.x == lab) ? 1.0f : 0.0f;
        o.y = (m.y == lab) ? 1.0f : 0.0f;
        o.z = (m.z == lab) ? 1.0f : 0.0f;
        o.w = (m.w == lab) ? 1.0f : 0.0f;
        *reinterpret_cast<float4*>(out + (size_t)n * V + i) = o;
    }
}

extern "C" void kernel_launch(void* const* d_in, const int* in_sizes, int n_in,
                              void* d_out, int out_size, void* d_ws, size_t ws_size,
                              hipStream_t stream) {
    const float* mask = (const float*)d_in[0];
    float* out = (float*)d_out;

    const int threads = 256;
    const int total_threads = V / 4;            // 786,432
    const int blocks = total_threads / threads; // 3,072

    onehot_kernel<<<blocks, threads, 0, stream>>>(mask, out);
}

// Round 2
// 474.197 us; speedup vs baseline: 1.0551x; 1.0551x over previous
//
#include <hip/hip_runtime.h>
#include <hip/hip_bf16.h>

// One-hot expansion: mask [1,1,256,256,48] fp32 labels in 0..40 ->
// out [1,40,256,256,48] fp32, out[n,v] = (mask[v] == n+1).
//
// R1 lesson: 40 interleaved store streams per wave (plane stride 12.6 MB)
// ran at 1 TB/s; the harness's fill kernel (single contiguous stream per
// wave) hits 6.3 TB/s. So: one plane per blockIdx.y, each thread does one
// float4 mask load + one contiguous float4 store. Mask (12.6 MB) is re-read
// once per plane but lives in L2/LLC (256 MB), so HBM fetch stays ~13 MB.

constexpr int V = 256 * 256 * 48;   // 3,145,728 voxels per plane
constexpr int N_LABELS = 40;

__global__ __launch_bounds__(256)
void onehot_kernel(const float* __restrict__ mask, float* __restrict__ out) {
    const int i = (blockIdx.x * blockDim.x + threadIdx.x) * 4;  // voxel index
    const int n = blockIdx.y;                                   // label plane
    const float lab = (float)(n + 1);

    const float4 m = *reinterpret_cast<const float4*>(mask + i);

    float4 o;
    o.x = (m.x == lab) ? 1.0f : 0.0f;
    o.y = (m.y == lab) ? 1.0f : 0.0f;
    o.z = (m.z == lab) ? 1.0f : 0.0f;
    o.w = (m.w == lab) ? 1.0f : 0.0f;

    *reinterpret_cast<float4*>(out + (size_t)n * V + i) = o;
}

extern "C" void kernel_launch(void* const* d_in, const int* in_sizes, int n_in,
                              void* d_out, int out_size, void* d_ws, size_t ws_size,
                              hipStream_t stream) {
    const float* mask = (const float*)d_in[0];
    float* out = (float*)d_out;

    const int threads = 256;
    const int blocks_x = (V / 4) / threads;  // 3,072 chunks per plane
    dim3 grid(blocks_x, N_LABELS);           // 122,880 blocks total

    onehot_kernel<<<grid, threads, 0, stream>>>(mask, out);
}